// Round 3
// baseline (962.435 us; speedup 1.0000x reference)
//
#include <hip/hip_runtime.h>

// Problem constants (fixed by reference)
#define NN   50000
#define NNP  50048   // padded to 391*128
#define NE   800000
#define DIN  512
#define DH   512
#define DE   256

// CSR padded to multiple of 8 per node, sentinel = NN (dis[NN]=0, t'[NN]=0 row)
#define CSR_CAP 1150016  // >= NE + 7*NN, multiple of 16 ints

typedef __bf16 bf16_t;
typedef __bf16 bf16x4 __attribute__((ext_vector_type(4)));
typedef __bf16 bf16x8 __attribute__((ext_vector_type(8)));
typedef float  f32x4  __attribute__((ext_vector_type(4)));
typedef _Float16 half_t;
typedef _Float16 half8 __attribute__((ext_vector_type(8)));

// ---------------- fused prep kernel ----------------
//   (a) X fp32 -> Xh/Xl bf16 split w/ zero pad rows
//   (b) indegree atomics
//   (c) csr sentinel prefill
//   (d) W1 -> bf16 h/l transpose split
//   (e,f) W2/W3 -> fp16 h + l*4096 transpose split (for 2-term f16 MFMA)
//   (g) combined head weights + bias (bf16)
#define PB_SPLIT 25024   // NNP*DIN/4/256 exactly
#define PB_IDEG  3125    // NE/256 exactly
#define PB_CSR   1124    // ceil(CSR_CAP/4/256)
#define PB_W1    1024    // 512*512/256
#define PB_W2    1024
#define PB_W3    512     // 512*256/256
#define PB_HEADW 80      // 80*256/256
#define PB_TOTAL (PB_SPLIT + PB_IDEG + PB_CSR + PB_W1 + PB_W2 + PB_W3 + PB_HEADW)

__global__ void k_prep(const float* __restrict__ X, bf16_t* __restrict__ Xh,
                       bf16_t* __restrict__ Xl, const int* __restrict__ dst,
                       int* __restrict__ indeg, int* __restrict__ csr,
                       const float* __restrict__ W1, bf16_t* __restrict__ B1h, bf16_t* __restrict__ B1l,
                       const float* __restrict__ W2, half_t* __restrict__ B2h, half_t* __restrict__ B2l,
                       const float* __restrict__ W3, half_t* __restrict__ B3h, half_t* __restrict__ B3l,
                       const float* __restrict__ We, const float* __restrict__ be,
                       const float* __restrict__ Wh, const float* __restrict__ bh,
                       const float* __restrict__ Wg, const float* __restrict__ bg,
                       bf16_t* __restrict__ Wth, bf16_t* __restrict__ Wtl,
                       float* __restrict__ bc) {
    int b = blockIdx.x;
    if (b < PB_SPLIT) {
        long idx = (long)b * 256 + threadIdx.x;      // < NNP*DIN/4
        long base = idx * 4;
        int row = (int)(base >> 9);                  // /DIN
        f32x4 v;
        if (row < NN) v = *(const f32x4*)(X + base);
        else { v[0] = 0.f; v[1] = 0.f; v[2] = 0.f; v[3] = 0.f; }
        bf16x4 h, l;
        #pragma unroll
        for (int c = 0; c < 4; ++c) {
            float f = v[c];
            bf16_t hh = (bf16_t)f;
            h[c] = hh;
            l[c] = (bf16_t)(f - (float)hh);
        }
        *(bf16x4*)(Xh + base) = h;
        *(bf16x4*)(Xl + base) = l;
        return;
    }
    b -= PB_SPLIT;
    if (b < PB_IDEG) {
        int i = b * 256 + threadIdx.x;               // NE exact
        atomicAdd(&indeg[dst[i]], 1);
        return;
    }
    b -= PB_IDEG;
    if (b < PB_CSR) {
        int i = b * 256 + threadIdx.x;
        if (i < CSR_CAP / 4) ((int4*)csr)[i] = make_int4(NN, NN, NN, NN);
        return;
    }
    b -= PB_CSR;
    if (b < PB_W1) {
        int idx = b * 256 + threadIdx.x;             // 512x512 exact
        int k = idx >> 9, n = idx & 511;
        float f = W1[idx];
        bf16_t h = (bf16_t)f;
        B1h[(size_t)n * DIN + k] = h;
        B1l[(size_t)n * DIN + k] = (bf16_t)(f - (float)h);
        return;
    }
    b -= PB_W1;
    if (b < PB_W2) {
        int idx = b * 256 + threadIdx.x;             // 512x512 exact
        int k = idx >> 9, n = idx & 511;
        float f = W2[idx];
        half_t h = (half_t)f;
        B2h[(size_t)n * DH + k] = h;
        B2l[(size_t)n * DH + k] = (half_t)((f - (float)h) * 4096.f);
        return;
    }
    b -= PB_W2;
    if (b < PB_W3) {
        int idx = b * 256 + threadIdx.x;             // 512x256 exact, W3[k][n]
        int k = idx >> 8, n = idx & 255;
        float f = W3[idx];
        half_t h = (half_t)f;
        B3h[(size_t)n * DH + k] = h;
        B3l[(size_t)n * DH + k] = (half_t)((f - (float)h) * 4096.f);
        return;
    }
    b -= PB_W3;
    {
        int idx = b * 256 + threadIdx.x;             // 80*256 exact
        int n = idx / 256, k = idx % 256;
        float f = 0.f;
        if (n < 7)       f = We[k * 7 + n];
        else if (n < 15) f = Wh[k * 8 + (n - 7)];
        else if (n < 72) f = Wg[k * 57 + (n - 15)];
        bf16_t h = (bf16_t)f;
        Wth[idx] = h;
        Wtl[idx] = (bf16_t)(f - (float)h);
        if (k == 0) {
            float bb = 0.f;
            if (n < 7)       bb = be[n];
            else if (n < 15) bb = bh[n - 7];
            else if (n < 72) bb = bg[n - 15];
            bc[n] = bb;
        }
    }
}

// ---------------- parallel scan (3 small kernels) ----------------
#define SCAN_BLOCKS 49   // ceil(NN/1024)

__global__ __launch_bounds__(1024) void k_scan_a(const int* __restrict__ indeg,
                                                 int* __restrict__ rowptr,
                                                 float* __restrict__ dis,
                                                 int* __restrict__ bsum) {
    __shared__ int wsum[16];
    const int tid = threadIdx.x, lane = tid & 63, wid = tid >> 6;
    const int i = blockIdx.x * 1024 + tid;
    int deg = (i < NN) ? indeg[i] : 0;
    int v = (deg + 7) & ~7;                          // pad segment to %8
    int x = v;
    #pragma unroll
    for (int d = 1; d < 64; d <<= 1) {
        int t = __shfl_up(x, d, 64);
        if (lane >= d) x += t;
    }
    if (lane == 63) wsum[wid] = x;
    __syncthreads();
    if (wid == 0) {
        int s = (lane < 16) ? wsum[lane] : 0;
        #pragma unroll
        for (int d = 1; d < 16; d <<= 1) {
            int t = __shfl_up(s, d, 64);
            if (lane >= d) s += t;
        }
        if (lane < 16) wsum[lane] = s;               // inclusive wave prefix
    }
    __syncthreads();
    int woff = (wid > 0) ? wsum[wid - 1] : 0;
    if (i < NN) {
        rowptr[i] = x - v + woff;                    // local exclusive prefix
        dis[i] = rsqrtf((float)(deg + 1));
    } else if (i < NNP) {
        dis[i] = 0.f;                                // pad rows (incl. sentinel NN)
    }
    if (tid == 0) bsum[blockIdx.x] = wsum[15];       // block total
}

__global__ __launch_bounds__(64) void k_scan_b(const int* __restrict__ bsum,
                                               int* __restrict__ boff,
                                               int* __restrict__ rowptr) {
    const int lane = threadIdx.x;
    int v = (lane < SCAN_BLOCKS) ? bsum[lane] : 0;
    int x = v;
    #pragma unroll
    for (int d = 1; d < 64; d <<= 1) {
        int t = __shfl_up(x, d, 64);
        if (lane >= d) x += t;
    }
    if (lane < SCAN_BLOCKS) boff[lane] = x - v;      // exclusive block offset
    if (lane == SCAN_BLOCKS - 1) rowptr[NN] = x;     // grand total
}

__global__ void k_scan_c(const int* __restrict__ boff, int* __restrict__ rowptr,
                         int* __restrict__ cursor) {
    int i = blockIdx.x * blockDim.x + threadIdx.x;
    if (i < NN) {
        int r = rowptr[i] + boff[i >> 10];
        rowptr[i] = r;
        cursor[i] = r;
    }
}

__global__ void k_fill(const int* __restrict__ src, const int* __restrict__ dst,
                       int* __restrict__ cursor, int* __restrict__ csr, int e) {
    int i = blockIdx.x * blockDim.x + threadIdx.x;
    if (i < e) {
        int d = dst[i];
        int p = atomicAdd(&cursor[d], 1);
        csr[p] = src[i];
    }
}

// ---------------- GEMM helpers ----------------

__device__ __forceinline__ void gld_lds16(const void* g, void* l) {
    __builtin_amdgcn_global_load_lds(
        (const __attribute__((address_space(1))) unsigned int*)g,
        (__attribute__((address_space(3))) unsigned int*)l, 16, 0, 0);
}

// ---------------- layer-1 GEMM: 3-term split-bf16, dis-scaled fp16 out ----------------
// C[row,:] = (A@B)[row,:] * disv[row], A = Ah+Al bf16, Bt = Bh+Bl [N,K] bf16.
// 128x128 tile, BK=32, 256 threads. Grid exact (M=NNP), pad rows get disv=0 -> 0.

__global__ __launch_bounds__(256) void k_gemm_bf3(
    const bf16_t* __restrict__ Ah, const bf16_t* __restrict__ Al,
    const bf16_t* __restrict__ Bh, const bf16_t* __restrict__ Bl,  // [N,K]
    const float* __restrict__ disv,
    half_t* __restrict__ C, int N, int K) {
    __shared__ alignas(16) bf16_t sAh[128 * 32];
    __shared__ alignas(16) bf16_t sAl[128 * 32];
    __shared__ alignas(16) bf16_t sBh[128 * 32];
    __shared__ alignas(16) bf16_t sBl[128 * 32];

    const int tid = threadIdx.x;
    const int wave = tid >> 6, lane = tid & 63;
    const int quad = lane >> 4, l16 = lane & 15;
    const int bm = blockIdx.y * 128, bn = blockIdx.x * 128;
    const int wm = (wave & 1) * 64, wn = (wave >> 1) * 64;

    f32x4 acc[4][4];
    #pragma unroll
    for (int i = 0; i < 4; ++i)
        #pragma unroll
        for (int j = 0; j < 4; ++j)
            #pragma unroll
            for (int r = 0; r < 4; ++r) acc[i][j][r] = 0.f;

    const int srow = wave * 32 + (lane >> 2);
    const int sseg = (lane & 3) * 16;
    char* lds0A = (char*)sAh + wave * 32 * 64;
    char* lds0a = (char*)sAl + wave * 32 * 64;
    char* lds0B = (char*)sBh + wave * 32 * 64;
    char* lds0b = (char*)sBl + wave * 32 * 64;

    const char* gAh0 = (const char*)(Ah + (size_t)(bm + srow) * K) + sseg;
    const char* gAl0 = (const char*)(Al + (size_t)(bm + srow) * K) + sseg;
    const char* gBh0 = (const char*)(Bh + (size_t)(bn + srow) * K) + sseg;
    const char* gBl0 = (const char*)(Bl + (size_t)(bn + srow) * K) + sseg;
    const size_t rstep = (size_t)16 * K * 2;

    for (int k0 = 0; k0 < K; k0 += 32) {
        const size_t kb = (size_t)k0 * 2;
        gld_lds16(gAh0 + kb,         lds0A);
        gld_lds16(gAh0 + kb + rstep, lds0A + 1024);
        gld_lds16(gAl0 + kb,         lds0a);
        gld_lds16(gAl0 + kb + rstep, lds0a + 1024);
        gld_lds16(gBh0 + kb,         lds0B);
        gld_lds16(gBh0 + kb + rstep, lds0B + 1024);
        gld_lds16(gBl0 + kb,         lds0b);
        gld_lds16(gBl0 + kb + rstep, lds0b + 1024);
        __syncthreads();

        bf16x8 fah[4], fal[4], fbh[4], fbl[4];
        #pragma unroll
        for (int i = 0; i < 4; ++i) {
            fah[i] = *(const bf16x8*)(sAh + (wm + 16 * i + l16) * 32 + quad * 8);
            fal[i] = *(const bf16x8*)(sAl + (wm + 16 * i + l16) * 32 + quad * 8);
            fbh[i] = *(const bf16x8*)(sBh + (wn + 16 * i + l16) * 32 + quad * 8);
            fbl[i] = *(const bf16x8*)(sBl + (wn + 16 * i + l16) * 32 + quad * 8);
        }
        #pragma unroll
        for (int i = 0; i < 4; ++i)
            #pragma unroll
            for (int j = 0; j < 4; ++j) {
                acc[i][j] = __builtin_amdgcn_mfma_f32_16x16x32_bf16(fah[i], fbh[j], acc[i][j], 0, 0, 0);
                acc[i][j] = __builtin_amdgcn_mfma_f32_16x16x32_bf16(fah[i], fbl[j], acc[i][j], 0, 0, 0);
                acc[i][j] = __builtin_amdgcn_mfma_f32_16x16x32_bf16(fal[i], fbh[j], acc[i][j], 0, 0, 0);
            }
        __syncthreads();
    }

    #pragma unroll
    for (int i = 0; i < 4; ++i) {
        const int rowb = bm + wm + 16 * i + quad * 4;
        float d0 = disv[rowb], d1 = disv[rowb + 1], d2 = disv[rowb + 2], d3 = disv[rowb + 3];
        #pragma unroll
        for (int j = 0; j < 4; ++j) {
            int col = bn + wn + 16 * j + l16;
            C[(size_t)(rowb + 0) * N + col] = (half_t)(acc[i][j][0] * d0);
            C[(size_t)(rowb + 1) * N + col] = (half_t)(acc[i][j][1] * d1);
            C[(size_t)(rowb + 2) * N + col] = (half_t)(acc[i][j][2] * d2);
            C[(size_t)(rowb + 3) * N + col] = (half_t)(acc[i][j][3] * d3);
        }
    }
}

// ---------------- layers 2-3 GEMM: 2-term fp16 (A exact), dis-scaled fp16 out ----------
// C = (A @ (Bh + Bl/4096)) * disv[row]; A fp16 exact, Bh/Bl [N,K] fp16 (Bl pre-scaled 4096).

__global__ __launch_bounds__(256) void k_gemm_f16(
    const half_t* __restrict__ A,
    const half_t* __restrict__ Bh, const half_t* __restrict__ Bl,  // [N,K]
    const float* __restrict__ disv,
    half_t* __restrict__ C, int N, int K) {
    __shared__ alignas(16) half_t sA [128 * 32];
    __shared__ alignas(16) half_t sBh[128 * 32];
    __shared__ alignas(16) half_t sBl[128 * 32];

    const int tid = threadIdx.x;
    const int wave = tid >> 6, lane = tid & 63;
    const int quad = lane >> 4, l16 = lane & 15;
    const int bm = blockIdx.y * 128, bn = blockIdx.x * 128;
    const int wm = (wave & 1) * 64, wn = (wave >> 1) * 64;

    f32x4 aH[4][4], aM[4][4];
    #pragma unroll
    for (int i = 0; i < 4; ++i)
        #pragma unroll
        for (int j = 0; j < 4; ++j)
            #pragma unroll
            for (int r = 0; r < 4; ++r) { aH[i][j][r] = 0.f; aM[i][j][r] = 0.f; }

    const int srow = wave * 32 + (lane >> 2);
    const int sseg = (lane & 3) * 16;
    char* lds0A = (char*)sA  + wave * 32 * 64;
    char* lds0B = (char*)sBh + wave * 32 * 64;
    char* lds0b = (char*)sBl + wave * 32 * 64;

    const char* gA0  = (const char*)(A  + (size_t)(bm + srow) * K) + sseg;
    const char* gBh0 = (const char*)(Bh + (size_t)(bn + srow) * K) + sseg;
    const char* gBl0 = (const char*)(Bl + (size_t)(bn + srow) * K) + sseg;
    const size_t rstep = (size_t)16 * K * 2;

    for (int k0 = 0; k0 < K; k0 += 32) {
        const size_t kb = (size_t)k0 * 2;
        gld_lds16(gA0  + kb,         lds0A);
        gld_lds16(gA0  + kb + rstep, lds0A + 1024);
        gld_lds16(gBh0 + kb,         lds0B);
        gld_lds16(gBh0 + kb + rstep, lds0B + 1024);
        gld_lds16(gBl0 + kb,         lds0b);
        gld_lds16(gBl0 + kb + rstep, lds0b + 1024);
        __syncthreads();

        half8 fa[4], fbh[4], fbl[4];
        #pragma unroll
        for (int i = 0; i < 4; ++i) {
            fa[i]  = *(const half8*)(sA  + (wm + 16 * i + l16) * 32 + quad * 8);
            fbh[i] = *(const half8*)(sBh + (wn + 16 * i + l16) * 32 + quad * 8);
            fbl[i] = *(const half8*)(sBl + (wn + 16 * i + l16) * 32 + quad * 8);
        }
        #pragma unroll
        for (int i = 0; i < 4; ++i)
            #pragma unroll
            for (int j = 0; j < 4; ++j) {
                aH[i][j] = __builtin_amdgcn_mfma_f32_16x16x32_f16(fa[i], fbh[j], aH[i][j], 0, 0, 0);
                aM[i][j] = __builtin_amdgcn_mfma_f32_16x16x32_f16(fa[i], fbl[j], aM[i][j], 0, 0, 0);
            }
        __syncthreads();
    }

    const float s = 1.f / 4096.f;
    #pragma unroll
    for (int i = 0; i < 4; ++i) {
        const int rowb = bm + wm + 16 * i + quad * 4;
        float d0 = disv[rowb], d1 = disv[rowb + 1], d2 = disv[rowb + 2], d3 = disv[rowb + 3];
        #pragma unroll
        for (int j = 0; j < 4; ++j) {
            int col = bn + wn + 16 * j + l16;
            C[(size_t)(rowb + 0) * N + col] = (half_t)(fmaf(aM[i][j][0], s, aH[i][j][0]) * d0);
            C[(size_t)(rowb + 1) * N + col] = (half_t)(fmaf(aM[i][j][1], s, aH[i][j][1]) * d1);
            C[(size_t)(rowb + 2) * N + col] = (half_t)(fmaf(aM[i][j][2], s, aH[i][j][2]) * d2);
            C[(size_t)(rowb + 3) * N + col] = (half_t)(fmaf(aM[i][j][3], s, aH[i][j][3]) * d3);
        }
    }
}

// ---------------- aggregation ----------------
// t' rows are pre-scaled by dis[src]; out[i] = (sum t'[src] + t'[i])*dis[i] + b.
// din folded into each message fma (v_fma_mix). No per-edge weight loads.
// CSR padded %8 with sentinel NN (t'[NN]=0 exactly).

// Layers 1-2: fused relu, single fp16 output (next GEMM A). D=512. 2 nodes/block.
__global__ __launch_bounds__(128) void k_agg16(
    const half_t* __restrict__ t, const int* __restrict__ rowptr,
    const int* __restrict__ csr, const float* __restrict__ dis,
    const float* __restrict__ bias, half_t* __restrict__ out) {
    const int node = blockIdx.x * 2 + (threadIdx.x >> 6);
    const int lane = threadIdx.x & 63;  // 64 lanes x 8 elems (16B loads)
    const int beg = rowptr[node], end = rowptr[node + 1];
    const float din = dis[node];
    const char* tc = (const char*)t;
    const unsigned lb = (unsigned)lane * 16u;

    float a0[8], a1[8], a2[8], a3[8];
    #pragma unroll
    for (int c = 0; c < 8; ++c) { a0[c] = 0.f; a1[c] = 0.f; a2[c] = 0.f; a3[c] = 0.f; }

    if (beg < end) {
        int4 sa = *(const int4*)(csr + beg);
        int4 sb = *(const int4*)(csr + beg + 4);
        half8 v0 = *(const half8*)(tc + (((unsigned)sa.x) << 10) + lb);
        half8 v1 = *(const half8*)(tc + (((unsigned)sa.y) << 10) + lb);
        half8 v2 = *(const half8*)(tc + (((unsigned)sa.z) << 10) + lb);
        half8 v3 = *(const half8*)(tc + (((unsigned)sa.w) << 10) + lb);
        half8 v4 = *(const half8*)(tc + (((unsigned)sb.x) << 10) + lb);
        half8 v5 = *(const half8*)(tc + (((unsigned)sb.y) << 10) + lb);
        half8 v6 = *(const half8*)(tc + (((unsigned)sb.z) << 10) + lb);
        half8 v7 = *(const half8*)(tc + (((unsigned)sb.w) << 10) + lb);
        int4 na = sa, nb = sb;
        if (beg + 8 < end) {
            na = *(const int4*)(csr + beg + 8);
            nb = *(const int4*)(csr + beg + 12);
        }
        for (int e = beg; e < end; ) {
            half8 u0 = v0, u1 = v1, u2 = v2, u3 = v3, u4 = v4, u5 = v5, u6 = v6, u7 = v7;
            e += 8;
            if (e < end) {
                v0 = *(const half8*)(tc + (((unsigned)na.x) << 10) + lb);
                v1 = *(const half8*)(tc + (((unsigned)na.y) << 10) + lb);
                v2 = *(const half8*)(tc + (((unsigned)na.z) << 10) + lb);
                v3 = *(const half8*)(tc + (((unsigned)na.w) << 10) + lb);
                v4 = *(const half8*)(tc + (((unsigned)nb.x) << 10) + lb);
                v5 = *(const half8*)(tc + (((unsigned)nb.y) << 10) + lb);
                v6 = *(const half8*)(tc + (((unsigned)nb.z) << 10) + lb);
                v7 = *(const half8*)(tc + (((unsigned)nb.w) << 10) + lb);
                if (e + 8 < end) {
                    na = *(const int4*)(csr + e + 8);
                    nb = *(const int4*)(csr + e + 12);
                }
            }
            #pragma unroll
            for (int c = 0; c < 8; ++c) {
                a0[c] = fmaf((float)u0[c], din, a0[c]);
                a1[c] = fmaf((float)u1[c], din, a1[c]);
                a2[c] = fmaf((float)u2[c], din, a2[c]);
                a3[c] = fmaf((float)u3[c], din, a3[c]);
                a0[c] = fmaf((float)u4[c], din, a0[c]);
                a1[c] = fmaf((float)u5[c], din, a1[c]);
                a2[c] = fmaf((float)u6[c], din, a2[c]);
                a3[c] = fmaf((float)u7[c], din, a3[c]);
            }
        }
    }

    half8 sv = ((const half8*)(t + (size_t)node * DH))[lane];
    f32x4 bv0 = ((const f32x4*)bias)[lane * 2];
    f32x4 bv1 = ((const f32x4*)bias)[lane * 2 + 1];
    half8 h;
    #pragma unroll
    for (int c = 0; c < 8; ++c) {
        float b = (c < 4) ? bv0[c] : bv1[c - 4];
        float acc = (a0[c] + a1[c]) + (a2[c] + a3[c]);
        float o = fmaf((float)sv[c], din, acc) + b;
        o = fmaxf(o, 0.f);
        h[c] = (half_t)o;
    }
    *(half8*)(out + (size_t)node * DH + lane * 8) = h;
}

// Layer 3: fp32 emb + bf16 hi/lo split (feeds MFMA heads), no relu. D=256. 4 nodes/block.
__global__ __launch_bounds__(128) void k_agg_f32(
    const half_t* __restrict__ t, const int* __restrict__ rowptr,
    const int* __restrict__ csr, const float* __restrict__ dis,
    const float* __restrict__ bias, float* __restrict__ out,
    bf16_t* __restrict__ Eh, bf16_t* __restrict__ El) {
    const int node = blockIdx.x * 4 + (threadIdx.x >> 5);
    const int lane = threadIdx.x & 31;  // 32 lanes x 8 elems (16B loads)
    const int beg = rowptr[node], end = rowptr[node + 1];
    const float din = dis[node];
    const char* tc = (const char*)t;
    const unsigned lb = (unsigned)lane * 16u;

    float a0[8], a1[8], a2[8], a3[8];
    #pragma unroll
    for (int c = 0; c < 8; ++c) { a0[c] = 0.f; a1[c] = 0.f; a2[c] = 0.f; a3[c] = 0.f; }

    if (beg < end) {
        int4 sa = *(const int4*)(csr + beg);
        int4 sb = *(const int4*)(csr + beg + 4);
        half8 v0 = *(const half8*)(tc + (((unsigned)sa.x) << 9) + lb);
        half8 v1 = *(const half8*)(tc + (((unsigned)sa.y) << 9) + lb);
        half8 v2 = *(const half8*)(tc + (((unsigned)sa.z) << 9) + lb);
        half8 v3 = *(const half8*)(tc + (((unsigned)sa.w) << 9) + lb);
        half8 v4 = *(const half8*)(tc + (((unsigned)sb.x) << 9) + lb);
        half8 v5 = *(const half8*)(tc + (((unsigned)sb.y) << 9) + lb);
        half8 v6 = *(const half8*)(tc + (((unsigned)sb.z) << 9) + lb);
        half8 v7 = *(const half8*)(tc + (((unsigned)sb.w) << 9) + lb);
        int4 na = sa, nb = sb;
        if (beg + 8 < end) {
            na = *(const int4*)(csr + beg + 8);
            nb = *(const int4*)(csr + beg + 12);
        }
        for (int e = beg; e < end; ) {
            half8 u0 = v0, u1 = v1, u2 = v2, u3 = v3, u4 = v4, u5 = v5, u6 = v6, u7 = v7;
            e += 8;
            if (e < end) {
                v0 = *(const half8*)(tc + (((unsigned)na.x) << 9) + lb);
                v1 = *(const half8*)(tc + (((unsigned)na.y) << 9) + lb);
                v2 = *(const half8*)(tc + (((unsigned)na.z) << 9) + lb);
                v3 = *(const half8*)(tc + (((unsigned)na.w) << 9) + lb);
                v4 = *(const half8*)(tc + (((unsigned)nb.x) << 9) + lb);
                v5 = *(const half8*)(tc + (((unsigned)nb.y) << 9) + lb);
                v6 = *(const half8*)(tc + (((unsigned)nb.z) << 9) + lb);
                v7 = *(const half8*)(tc + (((unsigned)nb.w) << 9) + lb);
                if (e + 8 < end) {
                    na = *(const int4*)(csr + e + 8);
                    nb = *(const int4*)(csr + e + 12);
                }
            }
            #pragma unroll
            for (int c = 0; c < 8; ++c) {
                a0[c] = fmaf((float)u0[c], din, a0[c]);
                a1[c] = fmaf((float)u1[c], din, a1[c]);
                a2[c] = fmaf((float)u2[c], din, a2[c]);
                a3[c] = fmaf((float)u3[c], din, a3[c]);
                a0[c] = fmaf((float)u4[c], din, a0[c]);
                a1[c] = fmaf((float)u5[c], din, a1[c]);
                a2[c] = fmaf((float)u6[c], din, a2[c]);
                a3[c] = fmaf((float)u7[c], din, a3[c]);
            }
        }
    }

    half8 sv = ((const half8*)(t + (size_t)node * DE))[lane];
    f32x4 bv0 = ((const f32x4*)bias)[lane * 2];
    f32x4 bv1 = ((const f32x4*)bias)[lane * 2 + 1];
    f32x4 o0, o1;
    bf16x8 hh, ll;
    #pragma unroll
    for (int c = 0; c < 8; ++c) {
        float b = (c < 4) ? bv0[c] : bv1[c - 4];
        float acc = (a0[c] + a1[c]) + (a2[c] + a3[c]);
        float o = fmaf((float)sv[c], din, acc) + b;
        if (c < 4) o0[c] = o; else o1[c - 4] = o;
        bf16_t h = (bf16_t)o;
        hh[c] = h;
        ll[c] = (bf16_t)(o - (float)h);
    }
    ((f32x4*)(out + (size_t)node * DE))[lane * 2]     = o0;
    ((f32x4*)(out + (size_t)node * DE))[lane * 2 + 1] = o1;
    *(bf16x8*)(Eh + (size_t)node * DE + lane * 8) = hh;
    *(bf16x8*)(El + (size_t)node * DE + lane * 8) = ll;
}

// ---------------- MFMA heads: emb[NNP,256] @ Wt[80,256] -> {oe,oh,og} ----------------

__global__ __launch_bounds__(256) void k_heads_mfma(
    const bf16_t* __restrict__ Eh, const bf16_t* __restrict__ El,
    const bf16_t* __restrict__ Wth, const bf16_t* __restrict__ Wtl,
    const float* __restrict__ bc,
    float* __restrict__ oe, float* __restrict__ oh, float* __restrict__ og) {
    const int wave = threadIdx.x >> 6, lane = threadIdx.x & 63;
    const int quad = lane >> 4, l16 = lane & 15;
    const int row0 = blockIdx.x * 64 + wave * 16;

    f32x4 acc[5];
    #pragma unroll
    for (int j = 0; j < 5; ++j)
        #pragma unroll
        for (int r = 0; r < 4; ++r) acc[j][r] = 0.f;

    const size_t abase = (size_t)(row0 + l16) * 256 + quad * 8;
    #pragma unroll
    for (int ks = 0; ks < 256; ks += 32) {
        bf16x8 ah = *(const bf16x8*)(Eh + abase + ks);
        bf16x8 al = *(const bf16x8*)(El + abase + ks);
        #pragma unroll
        for (int j = 0; j < 5; ++j) {
            const size_t bbase = (size_t)(j * 16 + l16) * 256 + ks + quad * 8;
            bf16x8 bh = *(const bf16x8*)(Wth + bbase);
            bf16x8 bl = *(const bf16x8*)(Wtl + bbase);
            acc[j] = __builtin_amdgcn_mfma_f32_16x16x32_bf16(ah, bh, acc[j], 0, 0, 0);
            acc[j] = __builtin_amdgcn_mfma_f32_16x16x32_bf16(ah, bl, acc[j], 0, 0, 0);
            acc[j] = __builtin_amdgcn_mfma_f32_16x16x32_bf16(al, bh, acc[j], 0, 0, 0);
        }
    }

    #pragma unroll
    for (int j = 0; j < 5; ++j) {
        int col = j * 16 + l16;
        if (col < 72) {
            float b = bc[col];
            #pragma unroll
            for (int r = 0; r < 4; ++r) {
                int row = row0 + quad * 4 + r;
                if (row < NN) {
                    float v = acc[j][r] + b;
                    if (col < 7)       oe[(size_t)row * 7 + col] = v;
                    else if (col < 15) oh[(size_t)row * 8 + (col - 7)] = v;
                    else               og[(size_t)row * 57 + (col - 15)] = v;
                }
            }
        }
    }
}

// ---------------- launch ----------------

extern "C" void kernel_launch(void* const* d_in, const int* in_sizes, int n_in,
                              void* d_out, int out_size, void* d_ws, size_t ws_size,
                              hipStream_t stream) {
    const float* x   = (const float*)d_in[0];
    const int*   ei  = (const int*)d_in[1];
    const float* W1  = (const float*)d_in[2];
    const float* b1  = (const float*)d_in[3];
    const float* W2  = (const float*)d_in[4];
    const float* b2  = (const float*)d_in[5];
    const float* W3  = (const float*)d_in[6];
    const float* b3  = (const float*)d_in[7];
    const float* We  = (const float*)d_in[8];
    const float* be  = (const float*)d_in[9];
    const float* Wh  = (const float*)d_in[10];
    const float* bh  = (const float*)d_in[11];
    const float* Wg  = (const float*)d_in[12];
    const float* bg  = (const float*)d_in[13];

    const int* e_src = ei;
    const int* e_dst = ei + NE;

    // workspace layout (~162 MB, with aliasing):
    //   buf0: GEMM outputs t' (fp16 NNP x 512)
    //   buf1 (= Xh bytes): agg outputs / next GEMM A (fp16); Xh bf16 written by prep
    //   Xl (bf16) aliased with embh+embl (written much later by agg3)
    half_t* buf0 = (half_t*)d_ws;
    half_t* buf1 = buf0 + (size_t)NNP * DH;
    bf16_t* Xh   = (bf16_t*)buf1;
    bf16_t* Xl   = Xh + (size_t)NNP * DH;
    bf16_t* embh = Xl;                                  // NNP*DE
    bf16_t* embl = embh + (size_t)NNP * DE;             // 2*NNP*DE == NNP*DH: exact fit
    bf16_t* B1h  = Xl + (size_t)NNP * DH;
    bf16_t* B1l  = B1h + (size_t)DIN * DH;
    half_t* B2h  = (half_t*)(B1l + (size_t)DIN * DH);
    half_t* B2l  = B2h + (size_t)DH * DH;
    half_t* B3h  = B2l + (size_t)DH * DH;
    half_t* B3l  = B3h + (size_t)DE * DH;
    bf16_t* Wth  = (bf16_t*)(B3l + (size_t)DE * DH);
    bf16_t* Wtl  = Wth + 80 * 256;
    float*  bc   = (float*)(Wtl + 80 * 256);            // 80 fp32 (pad 128)
    int*   indeg  = (int*)(bc + 128);
    int*   rowptr = indeg + 50048;                      // 50001 used
    int*   cursor = rowptr + 50048;
    float* dis    = (float*)(cursor + 50048);           // NNP floats (pad+sentinel = 0)
    int*   csr    = (int*)(dis + 50048);                // CSR_CAP
    int*   bsum   = csr + CSR_CAP;                      // 64
    int*   boff   = bsum + 64;                          // 64

    float* emb   = (float*)d_out;                       // 50000*256
    float* out_e = emb + (size_t)NN * DE;               // 50000*7
    float* out_h = out_e + (size_t)NN * 7;              // 50000*8
    float* out_g = out_h + (size_t)NN * 8;              // 50000*57

    // 1) prep: zero indeg, then all input-only transforms in one wide launch
    hipMemsetAsync(indeg, 0, NN * sizeof(int), stream);
    k_prep<<<PB_TOTAL, 256, 0, stream>>>(x, Xh, Xl, e_dst, indeg, csr,
                                         W1, B1h, B1l, W2, B2h, B2l, W3, B3h, B3l,
                                         We, be, Wh, bh, Wg, bg, Wth, Wtl, bc);
    // 2) parallel scan + CSR fill
    k_scan_a<<<SCAN_BLOCKS, 1024, 0, stream>>>(indeg, rowptr, dis, bsum);
    k_scan_b<<<1, 64, 0, stream>>>(bsum, boff, rowptr);
    k_scan_c<<<(NN + 255) / 256, 256, 0, stream>>>(boff, rowptr, cursor);
    k_fill<<<(NE + 255) / 256, 256, 0, stream>>>(e_src, e_dst, cursor, csr, NE);

    const int gy = NNP / 128;  // 391

    // 3) layer 1: bf16 3-term GEMM (x split), dis-scaled fp16 out
    k_gemm_bf3<<<dim3(DH / 128, gy), 256, 0, stream>>>(Xh, Xl, B1h, B1l, dis, buf0, DH, DIN);
    k_agg16<<<NN / 2, 128, 0, stream>>>(buf0, rowptr, csr, dis, b1, buf1);

    // 4) layer 2: fp16 2-term GEMM (A exact), dis-scaled fp16 out
    k_gemm_f16<<<dim3(DH / 128, gy), 256, 0, stream>>>(buf1, B2h, B2l, dis, buf0, DH, DH);
    k_agg16<<<NN / 2, 128, 0, stream>>>(buf0, rowptr, csr, dis, b2, buf1);

    // 5) layer 3: fp16 2-term GEMM -> t3' (NNP x 256), then agg -> emb + head splits
    k_gemm_f16<<<dim3(DE / 128, gy), 256, 0, stream>>>(buf1, B3h, B3l, dis, buf0, DE, DH);
    k_agg_f32<<<NN / 4, 128, 0, stream>>>(buf0, rowptr, csr, dis, b3, emb, embh, embl);

    // 6) heads via MFMA
    k_heads_mfma<<<NNP / 64, 256, 0, stream>>>(embh, embl, Wth, Wtl, bc, out_e, out_h, out_g);
}

// Round 4
// 835.155 us; speedup vs baseline: 1.1524x; 1.1524x over previous
//
#include <hip/hip_runtime.h>

// Problem constants (fixed by reference)
#define NN   50000
#define NNP  50048   // padded to 391*128
#define NE   800000
#define DIN  512
#define DH   512
#define DE   256

// CSR padded to multiple of 8 per node, sentinel = NN (dis[NN]=0, t'[NN]=0 row)
#define CSR_CAP 1150016  // >= NE + 7*NN, multiple of 16 ints

typedef __bf16 bf16_t;
typedef __bf16 bf16x4 __attribute__((ext_vector_type(4)));
typedef __bf16 bf16x8 __attribute__((ext_vector_type(8)));
typedef float  f32x4  __attribute__((ext_vector_type(4)));
typedef _Float16 half_t;
typedef _Float16 half8 __attribute__((ext_vector_type(8)));

// ---------------- fused prep kernel ----------------
//   (a) X fp32 -> Xh/Xl bf16 split w/ zero pad rows
//   (b) indegree atomics
//   (c) csr sentinel prefill
//   (d) W1 -> bf16 h/l transpose split
//   (e,f) W2/W3 -> fp16 h + l*4096 transpose split (for 2-term f16 MFMA)
//   (g) combined head weights + bias (bf16)
#define PB_SPLIT 25024   // NNP*DIN/4/256 exactly
#define PB_IDEG  3125    // NE/256 exactly
#define PB_CSR   1124    // ceil(CSR_CAP/4/256)
#define PB_W1    1024    // 512*512/256
#define PB_W2    1024
#define PB_W3    512     // 512*256/256
#define PB_HEADW 80      // 80*256/256
#define PB_TOTAL (PB_SPLIT + PB_IDEG + PB_CSR + PB_W1 + PB_W2 + PB_W3 + PB_HEADW)

__global__ void k_prep(const float* __restrict__ X, bf16_t* __restrict__ Xh,
                       bf16_t* __restrict__ Xl, const int* __restrict__ dst,
                       int* __restrict__ indeg, int* __restrict__ csr,
                       const float* __restrict__ W1, bf16_t* __restrict__ B1h, bf16_t* __restrict__ B1l,
                       const float* __restrict__ W2, half_t* __restrict__ B2h, half_t* __restrict__ B2l,
                       const float* __restrict__ W3, half_t* __restrict__ B3h, half_t* __restrict__ B3l,
                       const float* __restrict__ We, const float* __restrict__ be,
                       const float* __restrict__ Wh, const float* __restrict__ bh,
                       const float* __restrict__ Wg, const float* __restrict__ bg,
                       bf16_t* __restrict__ Wth, bf16_t* __restrict__ Wtl,
                       float* __restrict__ bc) {
    int b = blockIdx.x;
    if (b < PB_SPLIT) {
        long idx = (long)b * 256 + threadIdx.x;      // < NNP*DIN/4
        long base = idx * 4;
        int row = (int)(base >> 9);                  // /DIN
        f32x4 v;
        if (row < NN) v = *(const f32x4*)(X + base);
        else { v[0] = 0.f; v[1] = 0.f; v[2] = 0.f; v[3] = 0.f; }
        bf16x4 h, l;
        #pragma unroll
        for (int c = 0; c < 4; ++c) {
            float f = v[c];
            bf16_t hh = (bf16_t)f;
            h[c] = hh;
            l[c] = (bf16_t)(f - (float)hh);
        }
        *(bf16x4*)(Xh + base) = h;
        *(bf16x4*)(Xl + base) = l;
        return;
    }
    b -= PB_SPLIT;
    if (b < PB_IDEG) {
        int i = b * 256 + threadIdx.x;               // NE exact
        atomicAdd(&indeg[dst[i]], 1);
        return;
    }
    b -= PB_IDEG;
    if (b < PB_CSR) {
        int i = b * 256 + threadIdx.x;
        if (i < CSR_CAP / 4) ((int4*)csr)[i] = make_int4(NN, NN, NN, NN);
        return;
    }
    b -= PB_CSR;
    if (b < PB_W1) {
        int idx = b * 256 + threadIdx.x;             // 512x512 exact
        int k = idx >> 9, n = idx & 511;
        float f = W1[idx];
        bf16_t h = (bf16_t)f;
        B1h[(size_t)n * DIN + k] = h;
        B1l[(size_t)n * DIN + k] = (bf16_t)(f - (float)h);
        return;
    }
    b -= PB_W1;
    if (b < PB_W2) {
        int idx = b * 256 + threadIdx.x;             // 512x512 exact
        int k = idx >> 9, n = idx & 511;
        float f = W2[idx];
        half_t h = (half_t)f;
        B2h[(size_t)n * DH + k] = h;
        B2l[(size_t)n * DH + k] = (half_t)((f - (float)h) * 4096.f);
        return;
    }
    b -= PB_W2;
    if (b < PB_W3) {
        int idx = b * 256 + threadIdx.x;             // 512x256 exact, W3[k][n]
        int k = idx >> 8, n = idx & 255;
        float f = W3[idx];
        half_t h = (half_t)f;
        B3h[(size_t)n * DH + k] = h;
        B3l[(size_t)n * DH + k] = (half_t)((f - (float)h) * 4096.f);
        return;
    }
    b -= PB_W3;
    {
        int idx = b * 256 + threadIdx.x;             // 80*256 exact
        int n = idx / 256, k = idx % 256;
        float f = 0.f;
        if (n < 7)       f = We[k * 7 + n];
        else if (n < 15) f = Wh[k * 8 + (n - 7)];
        else if (n < 72) f = Wg[k * 57 + (n - 15)];
        bf16_t h = (bf16_t)f;
        Wth[idx] = h;
        Wtl[idx] = (bf16_t)(f - (float)h);
        if (k == 0) {
            float bb = 0.f;
            if (n < 7)       bb = be[n];
            else if (n < 15) bb = bh[n - 7];
            else if (n < 72) bb = bg[n - 15];
            bc[n] = bb;
        }
    }
}

// ---------------- parallel scan (3 small kernels) ----------------
#define SCAN_BLOCKS 49   // ceil(NN/1024)

__global__ __launch_bounds__(1024) void k_scan_a(const int* __restrict__ indeg,
                                                 int* __restrict__ rowptr,
                                                 float* __restrict__ dis,
                                                 int* __restrict__ bsum) {
    __shared__ int wsum[16];
    const int tid = threadIdx.x, lane = tid & 63, wid = tid >> 6;
    const int i = blockIdx.x * 1024 + tid;
    int deg = (i < NN) ? indeg[i] : 0;
    int v = (deg + 7) & ~7;                          // pad segment to %8
    int x = v;
    #pragma unroll
    for (int d = 1; d < 64; d <<= 1) {
        int t = __shfl_up(x, d, 64);
        if (lane >= d) x += t;
    }
    if (lane == 63) wsum[wid] = x;
    __syncthreads();
    if (wid == 0) {
        int s = (lane < 16) ? wsum[lane] : 0;
        #pragma unroll
        for (int d = 1; d < 16; d <<= 1) {
            int t = __shfl_up(s, d, 64);
            if (lane >= d) s += t;
        }
        if (lane < 16) wsum[lane] = s;               // inclusive wave prefix
    }
    __syncthreads();
    int woff = (wid > 0) ? wsum[wid - 1] : 0;
    if (i < NN) {
        rowptr[i] = x - v + woff;                    // local exclusive prefix
        dis[i] = rsqrtf((float)(deg + 1));
    } else if (i < NNP) {
        dis[i] = 0.f;                                // pad rows (incl. sentinel NN)
    }
    if (tid == 0) bsum[blockIdx.x] = wsum[15];       // block total
}

__global__ __launch_bounds__(64) void k_scan_b(const int* __restrict__ bsum,
                                               int* __restrict__ boff,
                                               int* __restrict__ rowptr) {
    const int lane = threadIdx.x;
    int v = (lane < SCAN_BLOCKS) ? bsum[lane] : 0;
    int x = v;
    #pragma unroll
    for (int d = 1; d < 64; d <<= 1) {
        int t = __shfl_up(x, d, 64);
        if (lane >= d) x += t;
    }
    if (lane < SCAN_BLOCKS) boff[lane] = x - v;      // exclusive block offset
    if (lane == SCAN_BLOCKS - 1) rowptr[NN] = x;     // grand total
}

__global__ void k_scan_c(const int* __restrict__ boff, int* __restrict__ rowptr,
                         int* __restrict__ cursor) {
    int i = blockIdx.x * blockDim.x + threadIdx.x;
    if (i < NN) {
        int r = rowptr[i] + boff[i >> 10];
        rowptr[i] = r;
        cursor[i] = r;
    }
}

__global__ void k_fill(const int* __restrict__ src, const int* __restrict__ dst,
                       int* __restrict__ cursor, int* __restrict__ csr, int e) {
    int i = blockIdx.x * blockDim.x + threadIdx.x;
    if (i < e) {
        int d = dst[i];
        int p = atomicAdd(&cursor[d], 1);
        csr[p] = src[i];
    }
}

// ---------------- GEMM helpers ----------------

__device__ __forceinline__ void gld_lds16(const void* g, void* l) {
    __builtin_amdgcn_global_load_lds(
        (const __attribute__((address_space(1))) unsigned int*)g,
        (__attribute__((address_space(3))) unsigned int*)l, 16, 0, 0);
}

// LDS chunk swizzle: row r's 16B chunk q stored at slot q ^ ((r>>1)&3).
// Applied by swizzling the GLOBAL source (dest linear, as global_load_lds requires)
// and the fragment-read chunk index. Banks: 8-way -> 2-way (free).

// ---------------- layer-1 GEMM: 3-term split-bf16, dis-scaled fp16 out ----------------
// C[row,:] = (A@B)[row,:] * disv[row], A = Ah+Al bf16, Bt = Bh+Bl [N,K] bf16.
// 128x128 tile, BK=32, 256 threads. Grid exact (M=NNP), pad rows get disv=0 -> 0.

__global__ __launch_bounds__(256) void k_gemm_bf3(
    const bf16_t* __restrict__ Ah, const bf16_t* __restrict__ Al,
    const bf16_t* __restrict__ Bh, const bf16_t* __restrict__ Bl,  // [N,K]
    const float* __restrict__ disv,
    half_t* __restrict__ C, int N, int K) {
    __shared__ alignas(16) bf16_t sAh[128 * 32];
    __shared__ alignas(16) bf16_t sAl[128 * 32];
    __shared__ alignas(16) bf16_t sBh[128 * 32];
    __shared__ alignas(16) bf16_t sBl[128 * 32];

    const int tid = threadIdx.x;
    const int wave = tid >> 6, lane = tid & 63;
    const int quad = lane >> 4, l16 = lane & 15;
    const int bm = blockIdx.y * 128, bn = blockIdx.x * 128;
    const int wm = (wave & 1) * 64, wn = (wave >> 1) * 64;

    f32x4 acc[4][4];
    #pragma unroll
    for (int i = 0; i < 4; ++i)
        #pragma unroll
        for (int j = 0; j < 4; ++j)
            #pragma unroll
            for (int r = 0; r < 4; ++r) acc[i][j][r] = 0.f;

    const int srow = wave * 32 + (lane >> 2);
    // swizzled source chunk: (srow>>1)&3 == ((lane>>3)&3); same for srow+16
    const int schk = (((lane & 3) ^ ((lane >> 3) & 3))) * 16;
    char* lds0A = (char*)sAh + wave * 32 * 64;
    char* lds0a = (char*)sAl + wave * 32 * 64;
    char* lds0B = (char*)sBh + wave * 32 * 64;
    char* lds0b = (char*)sBl + wave * 32 * 64;

    const char* gAh0 = (const char*)(Ah + (size_t)(bm + srow) * K) + schk;
    const char* gAl0 = (const char*)(Al + (size_t)(bm + srow) * K) + schk;
    const char* gBh0 = (const char*)(Bh + (size_t)(bn + srow) * K) + schk;
    const char* gBl0 = (const char*)(Bl + (size_t)(bn + srow) * K) + schk;
    const size_t rstep = (size_t)16 * K * 2;

    const int rsw = (l16 >> 1) & 3;                  // read swizzle (rows wm+16i+l16)

    for (int k0 = 0; k0 < K; k0 += 32) {
        const size_t kb = (size_t)k0 * 2;
        gld_lds16(gAh0 + kb,         lds0A);
        gld_lds16(gAh0 + kb + rstep, lds0A + 1024);
        gld_lds16(gAl0 + kb,         lds0a);
        gld_lds16(gAl0 + kb + rstep, lds0a + 1024);
        gld_lds16(gBh0 + kb,         lds0B);
        gld_lds16(gBh0 + kb + rstep, lds0B + 1024);
        gld_lds16(gBl0 + kb,         lds0b);
        gld_lds16(gBl0 + kb + rstep, lds0b + 1024);
        __syncthreads();

        bf16x8 fah[4], fal[4], fbh[4], fbl[4];
        #pragma unroll
        for (int i = 0; i < 4; ++i) {
            fah[i] = *(const bf16x8*)(sAh + (wm + 16 * i + l16) * 32 + (quad ^ rsw) * 8);
            fal[i] = *(const bf16x8*)(sAl + (wm + 16 * i + l16) * 32 + (quad ^ rsw) * 8);
            fbh[i] = *(const bf16x8*)(sBh + (wn + 16 * i + l16) * 32 + (quad ^ rsw) * 8);
            fbl[i] = *(const bf16x8*)(sBl + (wn + 16 * i + l16) * 32 + (quad ^ rsw) * 8);
        }
        #pragma unroll
        for (int i = 0; i < 4; ++i)
            #pragma unroll
            for (int j = 0; j < 4; ++j) {
                acc[i][j] = __builtin_amdgcn_mfma_f32_16x16x32_bf16(fah[i], fbh[j], acc[i][j], 0, 0, 0);
                acc[i][j] = __builtin_amdgcn_mfma_f32_16x16x32_bf16(fah[i], fbl[j], acc[i][j], 0, 0, 0);
                acc[i][j] = __builtin_amdgcn_mfma_f32_16x16x32_bf16(fal[i], fbh[j], acc[i][j], 0, 0, 0);
            }
        __syncthreads();
    }

    #pragma unroll
    for (int i = 0; i < 4; ++i) {
        const int rowb = bm + wm + 16 * i + quad * 4;
        float d0 = disv[rowb], d1 = disv[rowb + 1], d2 = disv[rowb + 2], d3 = disv[rowb + 3];
        #pragma unroll
        for (int j = 0; j < 4; ++j) {
            int col = bn + wn + 16 * j + l16;
            C[(size_t)(rowb + 0) * N + col] = (half_t)(acc[i][j][0] * d0);
            C[(size_t)(rowb + 1) * N + col] = (half_t)(acc[i][j][1] * d1);
            C[(size_t)(rowb + 2) * N + col] = (half_t)(acc[i][j][2] * d2);
            C[(size_t)(rowb + 3) * N + col] = (half_t)(acc[i][j][3] * d3);
        }
    }
}

// ---------------- layers 2-3 GEMM: 2-term fp16 (A exact), dis-scaled fp16 out ----------
// C = (A @ (Bh + Bl/4096)) * disv[row]; A fp16 exact, Bh/Bl [N,K] fp16 (Bl pre-scaled 4096).
// 8 waves (512 thr), 128x128 tile; each wave 32x64 -> acc 2x(8 f32x4) = 64 regs total,
// fixing the round-3 occupancy collapse (2 full acc sets @64x64 = 128 AGPRs -> 1 wave/SIMD).

__global__ __launch_bounds__(512) void k_gemm_f16(
    const half_t* __restrict__ A,
    const half_t* __restrict__ Bh, const half_t* __restrict__ Bl,  // [N,K]
    const float* __restrict__ disv,
    half_t* __restrict__ C, int N, int K) {
    __shared__ alignas(16) half_t sA [128 * 32];
    __shared__ alignas(16) half_t sBh[128 * 32];
    __shared__ alignas(16) half_t sBl[128 * 32];

    const int tid = threadIdx.x;
    const int wave = tid >> 6, lane = tid & 63;
    const int quad = lane >> 4, l16 = lane & 15;
    const int bm = blockIdx.y * 128, bn = blockIdx.x * 128;
    const int wm = (wave >> 1) * 32, wn = (wave & 1) * 64;

    f32x4 aH[2][4], aM[2][4];
    #pragma unroll
    for (int i = 0; i < 2; ++i)
        #pragma unroll
        for (int j = 0; j < 4; ++j)
            #pragma unroll
            for (int r = 0; r < 4; ++r) { aH[i][j][r] = 0.f; aM[i][j][r] = 0.f; }

    // staging: wave w stages rows 16w..16w+15 (1KB) of each 8KB tile, 1 gld/thread
    const int srow = wave * 16 + (lane >> 2);
    const int schk = (((lane & 3) ^ ((lane >> 3) & 3))) * 16;  // swizzled src chunk
    char* ldsA = (char*)sA  + wave * 1024;
    char* ldsB = (char*)sBh + wave * 1024;
    char* ldsb = (char*)sBl + wave * 1024;

    const char* gA0  = (const char*)(A  + (size_t)(bm + srow) * K) + schk;
    const char* gBh0 = (const char*)(Bh + (size_t)(bn + srow) * K) + schk;
    const char* gBl0 = (const char*)(Bl + (size_t)(bn + srow) * K) + schk;

    const int rsw = (l16 >> 1) & 3;                  // read swizzle

    for (int k0 = 0; k0 < K; k0 += 32) {
        const size_t kb = (size_t)k0 * 2;
        gld_lds16(gA0  + kb, ldsA);
        gld_lds16(gBh0 + kb, ldsB);
        gld_lds16(gBl0 + kb, ldsb);
        __syncthreads();

        half8 fa[2], fbh[4], fbl[4];
        #pragma unroll
        for (int i = 0; i < 2; ++i)
            fa[i] = *(const half8*)(sA + (wm + 16 * i + l16) * 32 + (quad ^ rsw) * 8);
        #pragma unroll
        for (int j = 0; j < 4; ++j) {
            fbh[j] = *(const half8*)(sBh + (wn + 16 * j + l16) * 32 + (quad ^ rsw) * 8);
            fbl[j] = *(const half8*)(sBl + (wn + 16 * j + l16) * 32 + (quad ^ rsw) * 8);
        }
        #pragma unroll
        for (int i = 0; i < 2; ++i)
            #pragma unroll
            for (int j = 0; j < 4; ++j) {
                aH[i][j] = __builtin_amdgcn_mfma_f32_16x16x32_f16(fa[i], fbh[j], aH[i][j], 0, 0, 0);
                aM[i][j] = __builtin_amdgcn_mfma_f32_16x16x32_f16(fa[i], fbl[j], aM[i][j], 0, 0, 0);
            }
        __syncthreads();
    }

    const float s = 1.f / 4096.f;
    #pragma unroll
    for (int i = 0; i < 2; ++i) {
        const int rowb = bm + wm + 16 * i + quad * 4;
        float d0 = disv[rowb], d1 = disv[rowb + 1], d2 = disv[rowb + 2], d3 = disv[rowb + 3];
        #pragma unroll
        for (int j = 0; j < 4; ++j) {
            int col = bn + wn + 16 * j + l16;
            C[(size_t)(rowb + 0) * N + col] = (half_t)(fmaf(aM[i][j][0], s, aH[i][j][0]) * d0);
            C[(size_t)(rowb + 1) * N + col] = (half_t)(fmaf(aM[i][j][1], s, aH[i][j][1]) * d1);
            C[(size_t)(rowb + 2) * N + col] = (half_t)(fmaf(aM[i][j][2], s, aH[i][j][2]) * d2);
            C[(size_t)(rowb + 3) * N + col] = (half_t)(fmaf(aM[i][j][3], s, aH[i][j][3]) * d3);
        }
    }
}

// ---------------- aggregation ----------------
// t' rows are pre-scaled by dis[src]; out[i] = (sum t'[src] + t'[i])*dis[i] + b.
// CSR padded %8 with sentinel NN (t'[NN]=0 exactly).

// Layers 1-2: fused relu, single fp16 output (next GEMM A). D=512. 2 nodes/block.
__global__ __launch_bounds__(128) void k_agg16(
    const half_t* __restrict__ t, const int* __restrict__ rowptr,
    const int* __restrict__ csr, const float* __restrict__ dis,
    const float* __restrict__ bias, half_t* __restrict__ out) {
    const int node = blockIdx.x * 2 + (threadIdx.x >> 6);
    const int lane = threadIdx.x & 63;  // 64 lanes x 8 elems (16B loads)
    const int beg = rowptr[node], end = rowptr[node + 1];
    const float din = dis[node];
    const char* tc = (const char*)t;
    const unsigned lb = (unsigned)lane * 16u;

    float a0[8], a1[8], a2[8], a3[8];
    #pragma unroll
    for (int c = 0; c < 8; ++c) { a0[c] = 0.f; a1[c] = 0.f; a2[c] = 0.f; a3[c] = 0.f; }

    if (beg < end) {
        int4 sa = *(const int4*)(csr + beg);
        int4 sb = *(const int4*)(csr + beg + 4);
        half8 v0 = *(const half8*)(tc + (((unsigned)sa.x) << 10) + lb);
        half8 v1 = *(const half8*)(tc + (((unsigned)sa.y) << 10) + lb);
        half8 v2 = *(const half8*)(tc + (((unsigned)sa.z) << 10) + lb);
        half8 v3 = *(const half8*)(tc + (((unsigned)sa.w) << 10) + lb);
        half8 v4 = *(const half8*)(tc + (((unsigned)sb.x) << 10) + lb);
        half8 v5 = *(const half8*)(tc + (((unsigned)sb.y) << 10) + lb);
        half8 v6 = *(const half8*)(tc + (((unsigned)sb.z) << 10) + lb);
        half8 v7 = *(const half8*)(tc + (((unsigned)sb.w) << 10) + lb);
        int4 na = sa, nb = sb;
        if (beg + 8 < end) {
            na = *(const int4*)(csr + beg + 8);
            nb = *(const int4*)(csr + beg + 12);
        }
        for (int e = beg; e < end; ) {
            half8 u0 = v0, u1 = v1, u2 = v2, u3 = v3, u4 = v4, u5 = v5, u6 = v6, u7 = v7;
            e += 8;
            if (e < end) {
                v0 = *(const half8*)(tc + (((unsigned)na.x) << 10) + lb);
                v1 = *(const half8*)(tc + (((unsigned)na.y) << 10) + lb);
                v2 = *(const half8*)(tc + (((unsigned)na.z) << 10) + lb);
                v3 = *(const half8*)(tc + (((unsigned)na.w) << 10) + lb);
                v4 = *(const half8*)(tc + (((unsigned)nb.x) << 10) + lb);
                v5 = *(const half8*)(tc + (((unsigned)nb.y) << 10) + lb);
                v6 = *(const half8*)(tc + (((unsigned)nb.z) << 10) + lb);
                v7 = *(const half8*)(tc + (((unsigned)nb.w) << 10) + lb);
                if (e + 8 < end) {
                    na = *(const int4*)(csr + e + 8);
                    nb = *(const int4*)(csr + e + 12);
                }
            }
            #pragma unroll
            for (int c = 0; c < 8; ++c) {
                a0[c] = fmaf((float)u0[c], din, a0[c]);
                a1[c] = fmaf((float)u1[c], din, a1[c]);
                a2[c] = fmaf((float)u2[c], din, a2[c]);
                a3[c] = fmaf((float)u3[c], din, a3[c]);
                a0[c] = fmaf((float)u4[c], din, a0[c]);
                a1[c] = fmaf((float)u5[c], din, a1[c]);
                a2[c] = fmaf((float)u6[c], din, a2[c]);
                a3[c] = fmaf((float)u7[c], din, a3[c]);
            }
        }
    }

    half8 sv = ((const half8*)(t + (size_t)node * DH))[lane];
    f32x4 bv0 = ((const f32x4*)bias)[lane * 2];
    f32x4 bv1 = ((const f32x4*)bias)[lane * 2 + 1];
    half8 h;
    #pragma unroll
    for (int c = 0; c < 8; ++c) {
        float b = (c < 4) ? bv0[c] : bv1[c - 4];
        float acc = (a0[c] + a1[c]) + (a2[c] + a3[c]);
        float o = fmaf((float)sv[c], din, acc) + b;
        o = fmaxf(o, 0.f);
        h[c] = (half_t)o;
    }
    *(half8*)(out + (size_t)node * DH + lane * 8) = h;
}

// Layer 3: fp32 emb + bf16 hi/lo split (feeds MFMA heads), no relu. D=256. 4 nodes/block.
__global__ __launch_bounds__(128) void k_agg_f32(
    const half_t* __restrict__ t, const int* __restrict__ rowptr,
    const int* __restrict__ csr, const float* __restrict__ dis,
    const float* __restrict__ bias, float* __restrict__ out,
    bf16_t* __restrict__ Eh, bf16_t* __restrict__ El) {
    const int node = blockIdx.x * 4 + (threadIdx.x >> 5);
    const int lane = threadIdx.x & 31;  // 32 lanes x 8 elems (16B loads)
    const int beg = rowptr[node], end = rowptr[node + 1];
    const float din = dis[node];
    const char* tc = (const char*)t;
    const unsigned lb = (unsigned)lane * 16u;

    float a0[8], a1[8], a2[8], a3[8];
    #pragma unroll
    for (int c = 0; c < 8; ++c) { a0[c] = 0.f; a1[c] = 0.f; a2[c] = 0.f; a3[c] = 0.f; }

    if (beg < end) {
        int4 sa = *(const int4*)(csr + beg);
        int4 sb = *(const int4*)(csr + beg + 4);
        half8 v0 = *(const half8*)(tc + (((unsigned)sa.x) << 9) + lb);
        half8 v1 = *(const half8*)(tc + (((unsigned)sa.y) << 9) + lb);
        half8 v2 = *(const half8*)(tc + (((unsigned)sa.z) << 9) + lb);
        half8 v3 = *(const half8*)(tc + (((unsigned)sa.w) << 9) + lb);
        half8 v4 = *(const half8*)(tc + (((unsigned)sb.x) << 9) + lb);
        half8 v5 = *(const half8*)(tc + (((unsigned)sb.y) << 9) + lb);
        half8 v6 = *(const half8*)(tc + (((unsigned)sb.z) << 9) + lb);
        half8 v7 = *(const half8*)(tc + (((unsigned)sb.w) << 9) + lb);
        int4 na = sa, nb = sb;
        if (beg + 8 < end) {
            na = *(const int4*)(csr + beg + 8);
            nb = *(const int4*)(csr + beg + 12);
        }
        for (int e = beg; e < end; ) {
            half8 u0 = v0, u1 = v1, u2 = v2, u3 = v3, u4 = v4, u5 = v5, u6 = v6, u7 = v7;
            e += 8;
            if (e < end) {
                v0 = *(const half8*)(tc + (((unsigned)na.x) << 9) + lb);
                v1 = *(const half8*)(tc + (((unsigned)na.y) << 9) + lb);
                v2 = *(const half8*)(tc + (((unsigned)na.z) << 9) + lb);
                v3 = *(const half8*)(tc + (((unsigned)na.w) << 9) + lb);
                v4 = *(const half8*)(tc + (((unsigned)nb.x) << 9) + lb);
                v5 = *(const half8*)(tc + (((unsigned)nb.y) << 9) + lb);
                v6 = *(const half8*)(tc + (((unsigned)nb.z) << 9) + lb);
                v7 = *(const half8*)(tc + (((unsigned)nb.w) << 9) + lb);
                if (e + 8 < end) {
                    na = *(const int4*)(csr + e + 8);
                    nb = *(const int4*)(csr + e + 12);
                }
            }
            #pragma unroll
            for (int c = 0; c < 8; ++c) {
                a0[c] = fmaf((float)u0[c], din, a0[c]);
                a1[c] = fmaf((float)u1[c], din, a1[c]);
                a2[c] = fmaf((float)u2[c], din, a2[c]);
                a3[c] = fmaf((float)u3[c], din, a3[c]);
                a0[c] = fmaf((float)u4[c], din, a0[c]);
                a1[c] = fmaf((float)u5[c], din, a1[c]);
                a2[c] = fmaf((float)u6[c], din, a2[c]);
                a3[c] = fmaf((float)u7[c], din, a3[c]);
            }
        }
    }

    half8 sv = ((const half8*)(t + (size_t)node * DE))[lane];
    f32x4 bv0 = ((const f32x4*)bias)[lane * 2];
    f32x4 bv1 = ((const f32x4*)bias)[lane * 2 + 1];
    f32x4 o0, o1;
    bf16x8 hh, ll;
    #pragma unroll
    for (int c = 0; c < 8; ++c) {
        float b = (c < 4) ? bv0[c] : bv1[c - 4];
        float acc = (a0[c] + a1[c]) + (a2[c] + a3[c]);
        float o = fmaf((float)sv[c], din, acc) + b;
        if (c < 4) o0[c] = o; else o1[c - 4] = o;
        bf16_t h = (bf16_t)o;
        hh[c] = h;
        ll[c] = (bf16_t)(o - (float)h);
    }
    ((f32x4*)(out + (size_t)node * DE))[lane * 2]     = o0;
    ((f32x4*)(out + (size_t)node * DE))[lane * 2 + 1] = o1;
    *(bf16x8*)(Eh + (size_t)node * DE + lane * 8) = hh;
    *(bf16x8*)(El + (size_t)node * DE + lane * 8) = ll;
}

// ---------------- MFMA heads: emb[NNP,256] @ Wt[80,256] -> {oe,oh,og} ----------------

__global__ __launch_bounds__(256) void k_heads_mfma(
    const bf16_t* __restrict__ Eh, const bf16_t* __restrict__ El,
    const bf16_t* __restrict__ Wth, const bf16_t* __restrict__ Wtl,
    const float* __restrict__ bc,
    float* __restrict__ oe, float* __restrict__ oh, float* __restrict__ og) {
    const int wave = threadIdx.x >> 6, lane = threadIdx.x & 63;
    const int quad = lane >> 4, l16 = lane & 15;
    const int row0 = blockIdx.x * 64 + wave * 16;

    f32x4 acc[5];
    #pragma unroll
    for (int j = 0; j < 5; ++j)
        #pragma unroll
        for (int r = 0; r < 4; ++r) acc[j][r] = 0.f;

    const size_t abase = (size_t)(row0 + l16) * 256 + quad * 8;
    #pragma unroll
    for (int ks = 0; ks < 256; ks += 32) {
        bf16x8 ah = *(const bf16x8*)(Eh + abase + ks);
        bf16x8 al = *(const bf16x8*)(El + abase + ks);
        #pragma unroll
        for (int j = 0; j < 5; ++j) {
            const size_t bbase = (size_t)(j * 16 + l16) * 256 + ks + quad * 8;
            bf16x8 bh = *(const bf16x8*)(Wth + bbase);
            bf16x8 bl = *(const bf16x8*)(Wtl + bbase);
            acc[j] = __builtin_amdgcn_mfma_f32_16x16x32_bf16(ah, bh, acc[j], 0, 0, 0);
            acc[j] = __builtin_amdgcn_mfma_f32_16x16x32_bf16(ah, bl, acc[j], 0, 0, 0);
            acc[j] = __builtin_amdgcn_mfma_f32_16x16x32_bf16(al, bh, acc[j], 0, 0, 0);
        }
    }

    #pragma unroll
    for (int j = 0; j < 5; ++j) {
        int col = j * 16 + l16;
        if (col < 72) {
            float b = bc[col];
            #pragma unroll
            for (int r = 0; r < 4; ++r) {
                int row = row0 + quad * 4 + r;
                if (row < NN) {
                    float v = acc[j][r] + b;
                    if (col < 7)       oe[(size_t)row * 7 + col] = v;
                    else if (col < 15) oh[(size_t)row * 8 + (col - 7)] = v;
                    else               og[(size_t)row * 57 + (col - 15)] = v;
                }
            }
        }
    }
}

// ---------------- launch ----------------

extern "C" void kernel_launch(void* const* d_in, const int* in_sizes, int n_in,
                              void* d_out, int out_size, void* d_ws, size_t ws_size,
                              hipStream_t stream) {
    const float* x   = (const float*)d_in[0];
    const int*   ei  = (const int*)d_in[1];
    const float* W1  = (const float*)d_in[2];
    const float* b1  = (const float*)d_in[3];
    const float* W2  = (const float*)d_in[4];
    const float* b2  = (const float*)d_in[5];
    const float* W3  = (const float*)d_in[6];
    const float* b3  = (const float*)d_in[7];
    const float* We  = (const float*)d_in[8];
    const float* be  = (const float*)d_in[9];
    const float* Wh  = (const float*)d_in[10];
    const float* bh  = (const float*)d_in[11];
    const float* Wg  = (const float*)d_in[12];
    const float* bg  = (const float*)d_in[13];

    const int* e_src = ei;
    const int* e_dst = ei + NE;

    // workspace layout (~162 MB, with aliasing):
    //   buf0: GEMM outputs t' (fp16 NNP x 512)
    //   buf1 (= Xh bytes): agg outputs / next GEMM A (fp16); Xh bf16 written by prep
    //   Xl (bf16) aliased with embh+embl (written much later by agg3)
    half_t* buf0 = (half_t*)d_ws;
    half_t* buf1 = buf0 + (size_t)NNP * DH;
    bf16_t* Xh   = (bf16_t*)buf1;
    bf16_t* Xl   = Xh + (size_t)NNP * DH;
    bf16_t* embh = Xl;                                  // NNP*DE
    bf16_t* embl = embh + (size_t)NNP * DE;             // 2*NNP*DE == NNP*DH: exact fit
    bf16_t* B1h  = Xl + (size_t)NNP * DH;
    bf16_t* B1l  = B1h + (size_t)DIN * DH;
    half_t* B2h  = (half_t*)(B1l + (size_t)DIN * DH);
    half_t* B2l  = B2h + (size_t)DH * DH;
    half_t* B3h  = B2l + (size_t)DH * DH;
    half_t* B3l  = B3h + (size_t)DE * DH;
    bf16_t* Wth  = (bf16_t*)(B3l + (size_t)DE * DH);
    bf16_t* Wtl  = Wth + 80 * 256;
    float*  bc   = (float*)(Wtl + 80 * 256);            // 80 fp32 (pad 128)
    int*   indeg  = (int*)(bc + 128);
    int*   rowptr = indeg + 50048;                      // 50001 used
    int*   cursor = rowptr + 50048;
    float* dis    = (float*)(cursor + 50048);           // NNP floats (pad+sentinel = 0)
    int*   csr    = (int*)(dis + 50048);                // CSR_CAP
    int*   bsum   = csr + CSR_CAP;                      // 64
    int*   boff   = bsum + 64;                          // 64

    float* emb   = (float*)d_out;                       // 50000*256
    float* out_e = emb + (size_t)NN * DE;               // 50000*7
    float* out_h = out_e + (size_t)NN * 7;              // 50000*8
    float* out_g = out_h + (size_t)NN * 8;              // 50000*57

    // 1) prep: zero indeg, then all input-only transforms in one wide launch
    hipMemsetAsync(indeg, 0, NN * sizeof(int), stream);
    k_prep<<<PB_TOTAL, 256, 0, stream>>>(x, Xh, Xl, e_dst, indeg, csr,
                                         W1, B1h, B1l, W2, B2h, B2l, W3, B3h, B3l,
                                         We, be, Wh, bh, Wg, bg, Wth, Wtl, bc);
    // 2) parallel scan + CSR fill
    k_scan_a<<<SCAN_BLOCKS, 1024, 0, stream>>>(indeg, rowptr, dis, bsum);
    k_scan_b<<<1, 64, 0, stream>>>(bsum, boff, rowptr);
    k_scan_c<<<(NN + 255) / 256, 256, 0, stream>>>(boff, rowptr, cursor);
    k_fill<<<(NE + 255) / 256, 256, 0, stream>>>(e_src, e_dst, cursor, csr, NE);

    const int gy = NNP / 128;  // 391

    // 3) layer 1: bf16 3-term GEMM (x split), dis-scaled fp16 out
    k_gemm_bf3<<<dim3(DH / 128, gy), 256, 0, stream>>>(Xh, Xl, B1h, B1l, dis, buf0, DH, DIN);
    k_agg16<<<NN / 2, 128, 0, stream>>>(buf0, rowptr, csr, dis, b1, buf1);

    // 4) layer 2: fp16 2-term GEMM (A exact, 8-wave), dis-scaled fp16 out
    k_gemm_f16<<<dim3(DH / 128, gy), 512, 0, stream>>>(buf1, B2h, B2l, dis, buf0, DH, DH);
    k_agg16<<<NN / 2, 128, 0, stream>>>(buf0, rowptr, csr, dis, b2, buf1);

    // 5) layer 3: fp16 2-term GEMM -> t3' (NNP x 256), then agg -> emb + head splits
    k_gemm_f16<<<dim3(DE / 128, gy), 512, 0, stream>>>(buf1, B3h, B3l, dis, buf0, DE, DH);
    k_agg_f32<<<NN / 4, 128, 0, stream>>>(buf0, rowptr, csr, dis, b3, emb, embh, embl);

    // 6) heads via MFMA
    k_heads_mfma<<<NNP / 64, 256, 0, stream>>>(embh, embl, Wth, Wtl, bc, out_e, out_h, out_g);
}